// Round 13
// baseline (123.944 us; speedup 1.0000x reference)
//
#include <hip/hip_runtime.h>
#include <hip/hip_bf16.h>

// B=16, H=64, W=64, C=192, heads=8, key_dim=32, ks=3
// pixels = 65536; model dim = 256.
// QKV row (stride 864 bf16): [ q(256) | kv-interleaved(512): g -> k[4g..],v[4g..] | qb 8x12 (9 used) ]
// Zero row at pixel 65536 handles OOB neighbors.

typedef __bf16 bf16x8_t __attribute__((ext_vector_type(8)));
typedef float f32x4_t __attribute__((ext_vector_type(4)));

#define SCALE 0.17677669529663687f
#define QSTRIDE 864
#define ZROW 65536

static __device__ __forceinline__ unsigned short bfbits(float f) {
    return __builtin_bit_cast(unsigned short, __float2bfloat16(f));
}
static __device__ __forceinline__ float bf2f(unsigned short u) {
    return __bfloat162float(__builtin_bit_cast(__hip_bfloat16, u));
}
static __device__ __forceinline__ float lo16f(unsigned int u) {
    return __builtin_bit_cast(float, u << 16);
}
static __device__ __forceinline__ float hi16f(unsigned int u) {
    return __builtin_bit_cast(float, u & 0xffff0000u);
}

static __device__ __forceinline__ void gload_lds16(const void* g, void* l) {
    __builtin_amdgcn_global_load_lds((const __attribute__((address_space(1))) void*)g,
                                     (__attribute__((address_space(3))) void*)l, 16, 0, 0);
}

// ---------------------------------------------------------------- convert x -> bf16
// Memory-roofline kernel (~12 us). Fusing into the GEMM was tried (round 10) and
// cost ~40 us of GEMM time -- keep standalone.
__global__ void k_convert_x(const float* __restrict__ x, ushort4* __restrict__ xb, int n4) {
    int i = blockIdx.x * blockDim.x + threadIdx.x;
    const int stride = gridDim.x * blockDim.x;
    const float4* x4 = reinterpret_cast<const float4*>(x);
    for (; i < n4; i += stride) {
        float4 v = x4[i];
        ushort4 o;
        o.x = bfbits(v.x); o.y = bfbits(v.y); o.z = bfbits(v.z); o.w = bfbits(v.w);
        xb[i] = o;
    }
}

// ---------------------------------------------------------------- pack weights
__global__ void k_pack(const float* __restrict__ Wq, const float* __restrict__ Wk,
                       const float* __restrict__ Wv, const float* __restrict__ Wo,
                       const float* __restrict__ bq, const float* __restrict__ bk,
                       const float* __restrict__ bv,
                       __hip_bfloat16* __restrict__ WqkvT, __hip_bfloat16* __restrict__ WoT,
                       float* __restrict__ qkvBias, float* __restrict__ wvTab,
                       __hip_bfloat16* __restrict__ QKV) {
    const int idx = blockIdx.x * blockDim.x + threadIdx.x;
    const int T0 = 896 * 192;            // WqkvT
    const int T1 = T0 + 192 * 256;       // WoT
    const int T2 = T1 + 896;             // qkvBias
    const int T3 = T2 + 768;             // wvTab
    const int T4 = T3 + QSTRIDE;         // zero row
    if (idx < T0) {
        const int m = idx / 192, k = idx % 192;
        float v = 0.f;
        if (m < 256) {
            v = Wq[k * 256 + m] * SCALE;
        } else if (m < 768) {
            const int j = m - 256, g = j >> 3, r = j & 7;
            const int d = 4 * g + (r & 3);
            v = (r < 4) ? Wk[k * 256 + d] : Wv[k * 256 + d];
        } else if (m < 864) {
            const int j = m - 768, h = j / 12, n = j % 12;
            if (n < 9) {
                const float dj = (float)(n % 3 - 1), di = (float)(n / 3 - 1);
                float acc = 0.f;
                for (int d = 0; d < 32; ++d) {
                    const int c = h * 32 + d;
                    const float bkv = dj * Wk[192 * 256 + c] + di * Wk[193 * 256 + c] + bk[c];
                    acc += Wq[k * 256 + c] * bkv;
                }
                v = acc * SCALE;
            }
        }
        WqkvT[m * 192 + k] = __float2bfloat16(v);
    } else if (idx < T1) {
        const int j = idx - T0;
        const int c = j >> 8, hd = j & 255;
        WoT[j] = __float2bfloat16(Wo[hd * 192 + c]);
    } else if (idx < T2) {
        const int col = idx - T1;
        float v = 0.f;
        if (col < 256) v = bq[col] * SCALE;
        else if (col >= 768 && col < 864) {
            const int j = col - 768, h = j / 12, n = j % 12;
            if (n < 9) {
                const float dj = (float)(n % 3 - 1), di = (float)(n / 3 - 1);
                float acc = 0.f;
                for (int d = 0; d < 32; ++d) {
                    const int c = h * 32 + d;
                    const float bkv = dj * Wk[192 * 256 + c] + di * Wk[193 * 256 + c] + bk[c];
                    acc += bq[c] * bkv;
                }
                v = acc * SCALE;
            }
        }
        qkvBias[col] = v;
    } else if (idx < T3) {
        const int j = idx - T2;
        const int t = j >> 8, m = j & 255;
        float v;
        if (t == 0)      v = Wv[192 * 256 + m];
        else if (t == 1) v = Wv[193 * 256 + m];
        else             v = bv[m];
        wvTab[j] = v;
    } else if (idx < T4) {
        const int j = idx - T3;
        QKV[(size_t)ZROW * QSTRIDE + j] = __float2bfloat16(0.f);
    }
}

// ---------------------------------------------------------------- LDS-staged MFMA GEMM
// Round-12 base (swizzle, conflict-0) + T4 counted-vmcnt pipeline:
//   - double-buffered sA/sB; stage(t) and stage(t+1) issued before the loop
//   - raw s_barrier + inline-asm s_waitcnt vmcnt(L) where L = next stage's loads
//     (loads for t+1 stay IN FLIGHT across the barrier while compute(t) runs)
//   - stage(t+2) issued right after the post-compute read-barrier
// NO __syncthreads in the K-loop (its implicit vmcnt(0) drain was the r6/r7 stall).
template<int BM, int BN, int WRN, int WCN, int KDIM, int NOUT, int NBX, bool OUTF32, bool BIAS>
__global__ __launch_bounds__(256) void k_gemm_lds(const __hip_bfloat16* __restrict__ A,
                          const __hip_bfloat16* __restrict__ BT,
                          void* __restrict__ Cout,
                          const float* __restrict__ bias, int ldc) {
    constexpr int WTR = BM / WRN;
    constexpr int WTC = BN / WCN;
    constexpr int FR = WTR / 16;
    constexpr int FC = WTC / 16;
    constexpr int NK = KDIM / 64;
    constexpr int LPS = BM / 32 + BN / 32;          // gload_lds per wave per stage
    __shared__ __hip_bfloat16 sA[2][BM * 64];
    __shared__ __hip_bfloat16 sB[2][BN * 64];
    const int bid = blockIdx.x;
    const int s = (bid & 7) * ((int)gridDim.x >> 3) + (bid >> 3);
    const int by = s / NBX, bx = s - by * NBX;
    const int tid = threadIdx.x;
    const int wave = tid >> 6, lane = tid & 63;
    const int wr = wave / WCN, wc = wave % WCN;
    const long rowBase = (long)by * BM;
    const long colBase = (long)bx * BN;
    const int lr = lane & 15, lk = lane >> 4;
    const int rx = lr & 7;                          // row&7 of this lane's fragment rows
    const int srow = lane >> 3;                     // 0..7 within 8-row stage chunk
    const int scolsw = ((lane & 7) ^ srow) * 8;     // inverse-swizzled source elem offset

    auto stage = [&](int buf, int t) {
        const int k0 = t * 64;
        #pragma unroll
        for (int r = 0; r < BM / 32; ++r) {
            const int row0 = r * 32 + wave * 8;
            gload_lds16(A + (rowBase + row0 + srow) * KDIM + k0 + scolsw, &sA[buf][row0 * 64]);
        }
        #pragma unroll
        for (int r = 0; r < BN / 32; ++r) {
            const int row0 = r * 32 + wave * 8;
            gload_lds16(BT + (colBase + row0 + srow) * KDIM + k0 + scolsw, &sB[buf][row0 * 64]);
        }
    };

    f32x4_t acc[FR][FC] = {};
    stage(0, 0);
    stage(1, 1);                                    // NK >= 2 always here (3 or 4)

    #pragma unroll
    for (int t = 0; t < NK; ++t) {
        // wait for stage(t) only: allow stage(t+1)'s LPS loads to stay in flight
        if (t + 1 < NK) asm volatile("s_waitcnt vmcnt(%0)" :: "i"(LPS) : "memory");
        else            asm volatile("s_waitcnt vmcnt(0)" ::: "memory");
        __builtin_amdgcn_s_barrier();               // all waves' stage(t) landed
        __builtin_amdgcn_sched_barrier(0);
        #pragma unroll
        for (int kk = 0; kk < 2; ++kk) {
            const int pc = ((lk + kk * 4) ^ rx) * 8;   // swizzled phys chunk offset
            bf16x8_t a[FR], b[FC];
            #pragma unroll
            for (int fr = 0; fr < FR; ++fr)
                a[fr] = *reinterpret_cast<const bf16x8_t*>(&sA[t & 1][(wr * WTR + fr * 16 + lr) * 64 + pc]);
            #pragma unroll
            for (int fc = 0; fc < FC; ++fc)
                b[fc] = *reinterpret_cast<const bf16x8_t*>(&sB[t & 1][(wc * WTC + fc * 16 + lr) * 64 + pc]);
            #pragma unroll
            for (int fr = 0; fr < FR; ++fr) {
                #pragma unroll
                for (int fc = 0; fc < FC; ++fc)
                    acc[fr][fc] = __builtin_amdgcn_mfma_f32_16x16x32_bf16(a[fr], b[fc], acc[fr][fc], 0, 0, 0);
            }
        }
        __builtin_amdgcn_sched_barrier(0);
        __builtin_amdgcn_s_barrier();               // all waves done reading buf t&1
        if (t + 2 < NK) stage(t & 1, t + 2);        // overwrite now-safe buffer; overlaps next iter
    }

    const int rowSub = (lane >> 4) * 4;
    const int colSub = lane & 15;
    #pragma unroll
    for (int fr = 0; fr < FR; ++fr) {
        #pragma unroll
        for (int fc = 0; fc < FC; ++fc) {
            const long col = colBase + wc * WTC + fc * 16 + colSub;
            if (col >= NOUT) continue;
            float bvv = BIAS ? bias[col] : 0.f;
            #pragma unroll
            for (int r = 0; r < 4; ++r) {
                const long row = rowBase + wr * WTR + fr * 16 + rowSub + r;
                float v = acc[fr][fc][r] + bvv;
                if constexpr (OUTF32) ((float*)Cout)[row * ldc + col] = v;
                else ((__hip_bfloat16*)Cout)[row * ldc + col] = __float2bfloat16(v);
            }
        }
    }
}

// ---------------------------------------------------------------- attention gather
// One wave per pixel; lane (h=lane>>3, dg=lane&7) owns dims idx=h*32+dg*4.
// 9 neighbor gathers of 16B each: [k0..k3,v0..v3]. score_n = q.k_n + qb_n.
// o = inv*(sum_n p_n v_n + Ej*Wv192 + Ei*Wv193) + bv.
__global__ __launch_bounds__(256) void k_attn(const __hip_bfloat16* __restrict__ QKV,
                       const float* __restrict__ wvTab,
                       __hip_bfloat16* __restrict__ O) {
    const int wave = threadIdx.x >> 6;
    const int lane = threadIdx.x & 63;
    const int bid = blockIdx.x;
    const int sblk = (bid & 7) * 2048 + (bid >> 3);   // XCD-chunked swizzle (16384 wgs)
    const int p = sblk * 4 + wave;
    const int y = (p >> 6) & 63;
    const int xq = p & 63;
    const int h = lane >> 3, dg = lane & 7;
    const int idx = h * 32 + dg * 4;
    const __hip_bfloat16* rowQ = QKV + (size_t)p * QSTRIDE;

    const ushort4 qu = *reinterpret_cast<const ushort4*>(rowQ + idx);
    const float q0 = bf2f(qu.x), q1 = bf2f(qu.y), q2 = bf2f(qu.z), q3 = bf2f(qu.w);

    // qb: 9 values per head, padded to 12 -> 2x ushort4 + 1 scalar
    const ushort4 qba = *reinterpret_cast<const ushort4*>(rowQ + 768 + 12 * h);
    const ushort4 qbb = *reinterpret_cast<const ushort4*>(rowQ + 772 + 12 * h);
    const unsigned short qbc = *reinterpret_cast<const unsigned short*>(rowQ + 776 + 12 * h);
    float qb[9] = { bf2f(qba.x), bf2f(qba.y), bf2f(qba.z), bf2f(qba.w),
                    bf2f(qbb.x), bf2f(qbb.y), bf2f(qbb.z), bf2f(qbb.w), bf2f(qbc) };

    // branch-free neighbor gathers (OOB -> zero row), issued up front
    const char* baseQ = reinterpret_cast<const char*>(QKV);
    const long rowByte = (long)p * (QSTRIDE * 2);
    const int laneOff = 512 + 128 * h + 16 * dg;   // byte offset of this lane's kv group
    uint4 kv[9];
    #pragma unroll
    for (int n = 0; n < 9; ++n) {
        const int di = n / 3 - 1, dj = n % 3 - 1;
        const int ny = y + di, nx = xq + dj;
        const bool inb = ((unsigned)ny < 64u) & ((unsigned)nx < 64u);
        const long off = inb ? rowByte + (long)((di * 64 + dj) * (QSTRIDE * 2))
                             : (long)ZROW * (QSTRIDE * 2);
        kv[n] = *reinterpret_cast<const uint4*>(baseQ + off + laneOff);
    }

    float sc[9];
    #pragma unroll
    for (int n = 0; n < 9; ++n) {
        const float k0 = lo16f(kv[n].x), k1 = hi16f(kv[n].x);
        const float k2 = lo16f(kv[n].y), k3 = hi16f(kv[n].y);
        float ss = fmaf(q0, k0, fmaf(q1, k1, fmaf(q2, k2, q3 * k3)));
        ss += __shfl_xor(ss, 1);
        ss += __shfl_xor(ss, 2);
        ss += __shfl_xor(ss, 4);
        sc[n] = ss + qb[n];
    }
    float mx = sc[0];
    #pragma unroll
    for (int n = 1; n < 9; ++n) mx = fmaxf(mx, sc[n]);
    float sum = 0.f;
    #pragma unroll
    for (int n = 0; n < 9; ++n) { sc[n] = __expf(sc[n] - mx); sum += sc[n]; }
    const float inv = 1.0f / sum;
    const float Ej = (sc[2] + sc[5] + sc[8]) - (sc[0] + sc[3] + sc[6]);
    const float Ei = (sc[6] + sc[7] + sc[8]) - (sc[0] + sc[1] + sc[2]);

    float o0 = 0.f, o1 = 0.f, o2 = 0.f, o3 = 0.f;
    #pragma unroll
    for (int n = 0; n < 9; ++n) {
        o0 = fmaf(sc[n], lo16f(kv[n].z), o0);
        o1 = fmaf(sc[n], hi16f(kv[n].z), o1);
        o2 = fmaf(sc[n], lo16f(kv[n].w), o2);
        o3 = fmaf(sc[n], hi16f(kv[n].w), o3);
    }
    const float4 w0 = *reinterpret_cast<const float4*>(wvTab + idx);
    const float4 w1 = *reinterpret_cast<const float4*>(wvTab + 256 + idx);
    const float4 w2 = *reinterpret_cast<const float4*>(wvTab + 512 + idx);
    o0 = fmaf(Ej, w0.x, fmaf(Ei, w1.x, o0)) * inv + w2.x;
    o1 = fmaf(Ej, w0.y, fmaf(Ei, w1.y, o1)) * inv + w2.y;
    o2 = fmaf(Ej, w0.z, fmaf(Ei, w1.z, o2)) * inv + w2.z;
    o3 = fmaf(Ej, w0.w, fmaf(Ei, w1.w, o3)) * inv + w2.w;

    ushort4 ov;
    ov.x = bfbits(o0); ov.y = bfbits(o1); ov.z = bfbits(o2); ov.w = bfbits(o3);
    *reinterpret_cast<ushort4*>(O + (size_t)p * 256 + idx) = ov;
}

// ---------------------------------------------------------------- launch
extern "C" void kernel_launch(void* const* d_in, const int* in_sizes, int n_in,
                              void* d_out, int out_size, void* d_ws, size_t ws_size,
                              hipStream_t stream) {
    (void)in_sizes; (void)n_in; (void)out_size; (void)ws_size;
    const float* x  = (const float*)d_in[0];
    const float* Wq = (const float*)d_in[1];
    const float* bq = (const float*)d_in[2];
    const float* Wk = (const float*)d_in[3];
    const float* bk = (const float*)d_in[4];
    const float* Wv = (const float*)d_in[5];
    const float* bv = (const float*)d_in[6];
    const float* Wo = (const float*)d_in[7];
    const float* bo = (const float*)d_in[8];

    char* ws = (char*)d_ws;
    // ws layout (O overlaps dead xb; total ~147.3 MB):
    __hip_bfloat16* xb    = (__hip_bfloat16*)(ws + 0);           // 25,165,824 B
    __hip_bfloat16* O     = (__hip_bfloat16*)(ws + 0);           // 33,554,432 B (xb dead by then)
    __hip_bfloat16* QKV   = (__hip_bfloat16*)(ws + 33554432);    // 65537*864*2 = 113,247,936 B
    __hip_bfloat16* WqkvT = (__hip_bfloat16*)(ws + 146802368);   // 896*192*2 = 344,064
    __hip_bfloat16* WoT   = (__hip_bfloat16*)(ws + 147146432);   // 192*256*2 = 98,304
    float* qkvBias        = (float*)(ws + 147244736);            // 896*4 = 3,584
    float* wvTab          = (float*)(ws + 147248320);            // 3*256*4 = 3,072

    k_convert_x<<<4096, 256, 0, stream>>>(x, (ushort4*)xb, 12582912 / 4);
    k_pack<<<874, 256, 0, stream>>>(Wq, Wk, Wv, Wo, bq, bk, bv, WqkvT, WoT, qkvBias, wvTab, QKV);
    // QKV+QB projection: [65536,192] x [192,896(864 used)] -> bf16, stride 864
    k_gemm_lds<128, 128, 2, 2, 192, 864, 7, false, true>
        <<<3584, 256, 0, stream>>>(xb, WqkvT, (void*)QKV, qkvBias, QSTRIDE);
    // attention: one wave per pixel
    k_attn<<<16384, 256, 0, stream>>>(QKV, wvTab, O);
    // output projection: [65536,256] x [256,192] -> f32 + bo
    k_gemm_lds<128, 64, 2, 2, 256, 192, 3, true, true>
        <<<1536, 256, 0, stream>>>(O, WoT, d_out, bo, 192);
}

// Round 14
// 112.503 us; speedup vs baseline: 1.1017x; 1.1017x over previous
//
#include <hip/hip_runtime.h>
#include <hip/hip_bf16.h>

// B=16, H=64, W=64, C=192, heads=8, key_dim=32, ks=3
// pixels = 65536; model dim = 256.
// QKV row (stride 864 bf16): [ q(256) | kv-interleaved(512): g -> k[4g..],v[4g..] | qb 8x12 (9 used) ]
// Zero row at pixel 65536 handles OOB neighbors.

typedef __bf16 bf16x8_t __attribute__((ext_vector_type(8)));
typedef float f32x4_t __attribute__((ext_vector_type(4)));

#define SCALE 0.17677669529663687f
#define QSTRIDE 864
#define ZROW 65536

static __device__ __forceinline__ unsigned short bfbits(float f) {
    return __builtin_bit_cast(unsigned short, __float2bfloat16(f));
}
static __device__ __forceinline__ float bf2f(unsigned short u) {
    return __bfloat162float(__builtin_bit_cast(__hip_bfloat16, u));
}
static __device__ __forceinline__ float lo16f(unsigned int u) {
    return __builtin_bit_cast(float, u << 16);
}
static __device__ __forceinline__ float hi16f(unsigned int u) {
    return __builtin_bit_cast(float, u & 0xffff0000u);
}

static __device__ __forceinline__ void gload_lds16(const void* g, void* l) {
    __builtin_amdgcn_global_load_lds((const __attribute__((address_space(1))) void*)g,
                                     (__attribute__((address_space(3))) void*)l, 16, 0, 0);
}

// ---------------------------------------------------------------- convert x -> bf16
// Memory-roofline kernel (~12 us). Fusing into the GEMM was tried (round 10) and
// cost ~40 us of GEMM time -- keep standalone.
__global__ void k_convert_x(const float* __restrict__ x, ushort4* __restrict__ xb, int n4) {
    int i = blockIdx.x * blockDim.x + threadIdx.x;
    const int stride = gridDim.x * blockDim.x;
    const float4* x4 = reinterpret_cast<const float4*>(x);
    for (; i < n4; i += stride) {
        float4 v = x4[i];
        ushort4 o;
        o.x = bfbits(v.x); o.y = bfbits(v.y); o.z = bfbits(v.z); o.w = bfbits(v.w);
        xb[i] = o;
    }
}

// ---------------------------------------------------------------- pack weights
__global__ void k_pack(const float* __restrict__ Wq, const float* __restrict__ Wk,
                       const float* __restrict__ Wv, const float* __restrict__ Wo,
                       const float* __restrict__ bq, const float* __restrict__ bk,
                       const float* __restrict__ bv,
                       __hip_bfloat16* __restrict__ WqkvT, __hip_bfloat16* __restrict__ WoT,
                       float* __restrict__ qkvBias, float* __restrict__ wvTab,
                       __hip_bfloat16* __restrict__ QKV) {
    const int idx = blockIdx.x * blockDim.x + threadIdx.x;
    const int T0 = 896 * 192;            // WqkvT
    const int T1 = T0 + 192 * 256;       // WoT
    const int T2 = T1 + 896;             // qkvBias
    const int T3 = T2 + 768;             // wvTab
    const int T4 = T3 + QSTRIDE;         // zero row
    if (idx < T0) {
        const int m = idx / 192, k = idx % 192;
        float v = 0.f;
        if (m < 256) {
            v = Wq[k * 256 + m] * SCALE;
        } else if (m < 768) {
            const int j = m - 256, g = j >> 3, r = j & 7;
            const int d = 4 * g + (r & 3);
            v = (r < 4) ? Wk[k * 256 + d] : Wv[k * 256 + d];
        } else if (m < 864) {
            const int j = m - 768, h = j / 12, n = j % 12;
            if (n < 9) {
                const float dj = (float)(n % 3 - 1), di = (float)(n / 3 - 1);
                float acc = 0.f;
                for (int d = 0; d < 32; ++d) {
                    const int c = h * 32 + d;
                    const float bkv = dj * Wk[192 * 256 + c] + di * Wk[193 * 256 + c] + bk[c];
                    acc += Wq[k * 256 + c] * bkv;
                }
                v = acc * SCALE;
            }
        }
        WqkvT[m * 192 + k] = __float2bfloat16(v);
    } else if (idx < T1) {
        const int j = idx - T0;
        const int c = j >> 8, hd = j & 255;
        WoT[j] = __float2bfloat16(Wo[hd * 192 + c]);
    } else if (idx < T2) {
        const int col = idx - T1;
        float v = 0.f;
        if (col < 256) v = bq[col] * SCALE;
        else if (col >= 768 && col < 864) {
            const int j = col - 768, h = j / 12, n = j % 12;
            if (n < 9) {
                const float dj = (float)(n % 3 - 1), di = (float)(n / 3 - 1);
                float acc = 0.f;
                for (int d = 0; d < 32; ++d) {
                    const int c = h * 32 + d;
                    const float bkv = dj * Wk[192 * 256 + c] + di * Wk[193 * 256 + c] + bk[c];
                    acc += bq[c] * bkv;
                }
                v = acc * SCALE;
            }
        }
        qkvBias[col] = v;
    } else if (idx < T3) {
        const int j = idx - T2;
        const int t = j >> 8, m = j & 255;
        float v;
        if (t == 0)      v = Wv[192 * 256 + m];
        else if (t == 1) v = Wv[193 * 256 + m];
        else             v = bv[m];
        wvTab[j] = v;
    } else if (idx < T4) {
        const int j = idx - T3;
        QKV[(size_t)ZROW * QSTRIDE + j] = __float2bfloat16(0.f);
    }
}

// ---------------------------------------------------------------- LDS-staged MFMA GEMM
// Round-12 config (best measured: 49.3us QKV): single 32KB buffer, gload_lds A+B,
// XOR swizzle (conflict-0), 2 barriers per K-step. Deeper pipelining (r7/r13: 64KB
// dbuf, counted vmcnt) loses ~9us to the occupancy cliff at this 3-K-step shape.
template<int BM, int BN, int WRN, int WCN, int KDIM, int NOUT, int NBX, bool OUTF32, bool BIAS>
__global__ __launch_bounds__(256) void k_gemm_lds(const __hip_bfloat16* __restrict__ A,
                          const __hip_bfloat16* __restrict__ BT,
                          void* __restrict__ Cout,
                          const float* __restrict__ bias, int ldc) {
    constexpr int WTR = BM / WRN;
    constexpr int WTC = BN / WCN;
    constexpr int FR = WTR / 16;
    constexpr int FC = WTC / 16;
    constexpr int NK = KDIM / 64;
    __shared__ __hip_bfloat16 sA[BM * 64];
    __shared__ __hip_bfloat16 sB[BN * 64];
    const int bid = blockIdx.x;
    const int s = (bid & 7) * ((int)gridDim.x >> 3) + (bid >> 3);
    const int by = s / NBX, bx = s - by * NBX;
    const int tid = threadIdx.x;
    const int wave = tid >> 6, lane = tid & 63;
    const int wr = wave / WCN, wc = wave % WCN;
    const long rowBase = (long)by * BM;
    const long colBase = (long)bx * BN;
    const int lr = lane & 15, lk = lane >> 4;
    const int rx = lr & 7;                          // row&7 of this lane's fragment rows
    const int srow = lane >> 3;                     // 0..7 within 8-row stage chunk
    const int scolsw = ((lane & 7) ^ srow) * 8;     // inverse-swizzled source elem offset

    f32x4_t acc[FR][FC] = {};
    for (int t = 0; t < NK; ++t) {
        const int k0 = t * 64;
        #pragma unroll
        for (int r = 0; r < BM / 32; ++r) {
            const int row0 = r * 32 + wave * 8;
            gload_lds16(A + (rowBase + row0 + srow) * KDIM + k0 + scolsw, sA + row0 * 64);
        }
        #pragma unroll
        for (int r = 0; r < BN / 32; ++r) {
            const int row0 = r * 32 + wave * 8;
            gload_lds16(BT + (colBase + row0 + srow) * KDIM + k0 + scolsw, sB + row0 * 64);
        }
        __syncthreads();
        #pragma unroll
        for (int kk = 0; kk < 2; ++kk) {
            const int pc = ((lk + kk * 4) ^ rx) * 8;   // swizzled phys chunk offset
            bf16x8_t a[FR], b[FC];
            #pragma unroll
            for (int fr = 0; fr < FR; ++fr)
                a[fr] = *reinterpret_cast<const bf16x8_t*>(sA + (wr * WTR + fr * 16 + lr) * 64 + pc);
            #pragma unroll
            for (int fc = 0; fc < FC; ++fc)
                b[fc] = *reinterpret_cast<const bf16x8_t*>(sB + (wc * WTC + fc * 16 + lr) * 64 + pc);
            #pragma unroll
            for (int fr = 0; fr < FR; ++fr) {
                #pragma unroll
                for (int fc = 0; fc < FC; ++fc)
                    acc[fr][fc] = __builtin_amdgcn_mfma_f32_16x16x32_bf16(a[fr], b[fc], acc[fr][fc], 0, 0, 0);
            }
        }
        __syncthreads();
    }
    const int rowSub = (lane >> 4) * 4;
    const int colSub = lane & 15;
    #pragma unroll
    for (int fr = 0; fr < FR; ++fr) {
        #pragma unroll
        for (int fc = 0; fc < FC; ++fc) {
            const long col = colBase + wc * WTC + fc * 16 + colSub;
            if (col >= NOUT) continue;
            float bvv = BIAS ? bias[col] : 0.f;
            #pragma unroll
            for (int r = 0; r < 4; ++r) {
                const long row = rowBase + wr * WTR + fr * 16 + rowSub + r;
                float v = acc[fr][fc][r] + bvv;
                if constexpr (OUTF32) ((float*)Cout)[row * ldc + col] = v;
                else ((__hip_bfloat16*)Cout)[row * ldc + col] = __float2bfloat16(v);
            }
        }
    }
}

// ---------------------------------------------------------------- attention gather
// TWO adjacent pixels per wave (x even): union window = 3 rows x 4 cols = 12
// positions; pixels share 6 of 9 neighbors -> 12 gathers instead of 18 (-33%
// traffic, ~2x loads in flight). lane (h=lane>>3, dg=lane&7) owns dims
// idx=h*32+dg*4 for BOTH pixels. score_n = q.k_n + qb_n; v-bias via Ej/Ei fold.
__global__ __launch_bounds__(256) void k_attn(const __hip_bfloat16* __restrict__ QKV,
                       const float* __restrict__ wvTab,
                       __hip_bfloat16* __restrict__ O) {
    const int wave = threadIdx.x >> 6;
    const int lane = threadIdx.x & 63;
    const int bid = blockIdx.x;
    const int sblk = (bid & 7) * 1024 + (bid >> 3);   // XCD-chunked swizzle (8192 wgs)
    const int p0 = (sblk * 4 + wave) * 2;             // even pixel; p1 = p0+1 same row
    const int y = (p0 >> 6) & 63;
    const int x0 = p0 & 63;                           // even
    const int h = lane >> 3, dg = lane & 7;
    const int idx = h * 32 + dg * 4;
    const __hip_bfloat16* rowQ0 = QKV + (size_t)p0 * QSTRIDE;
    const __hip_bfloat16* rowQ1 = rowQ0 + QSTRIDE;

    const ushort4 qu0 = *reinterpret_cast<const ushort4*>(rowQ0 + idx);
    const ushort4 qu1 = *reinterpret_cast<const ushort4*>(rowQ1 + idx);

    // qb for both pixels: 2x (2x ushort4 + 1 scalar)
    const ushort4 qa0 = *reinterpret_cast<const ushort4*>(rowQ0 + 768 + 12 * h);
    const ushort4 qb0v = *reinterpret_cast<const ushort4*>(rowQ0 + 772 + 12 * h);
    const unsigned short qc0 = *reinterpret_cast<const unsigned short*>(rowQ0 + 776 + 12 * h);
    const ushort4 qa1 = *reinterpret_cast<const ushort4*>(rowQ1 + 768 + 12 * h);
    const ushort4 qb1v = *reinterpret_cast<const ushort4*>(rowQ1 + 772 + 12 * h);
    const unsigned short qc1 = *reinterpret_cast<const unsigned short*>(rowQ1 + 776 + 12 * h);

    // 12 branch-free gathers over the 3x4 union window (OOB -> zero row)
    const char* baseQ = reinterpret_cast<const char*>(QKV);
    const long rowByte = (long)p0 * (QSTRIDE * 2);
    const int laneOff = 512 + 128 * h + 16 * dg;
    uint4 kv[12];
    #pragma unroll
    for (int m = 0; m < 12; ++m) {
        const int rr = m >> 2, cc = m & 3;            // rr in [0,3), cc in [0,4)
        const int ny = y + rr - 1, nx = x0 + cc - 1;
        const bool inb = ((unsigned)ny < 64u) & ((unsigned)nx < 64u);
        const long off = inb ? rowByte + (long)(((rr - 1) * 64 + cc - 1) * (QSTRIDE * 2))
                             : (long)ZROW * (QSTRIDE * 2);
        kv[m] = *reinterpret_cast<const uint4*>(baseQ + off + laneOff);
    }

    const float q00 = bf2f(qu0.x), q01 = bf2f(qu0.y), q02 = bf2f(qu0.z), q03 = bf2f(qu0.w);
    const float q10 = bf2f(qu1.x), q11 = bf2f(qu1.y), q12 = bf2f(qu1.z), q13 = bf2f(qu1.w);
    float qb0[9] = { bf2f(qa0.x), bf2f(qa0.y), bf2f(qa0.z), bf2f(qa0.w),
                     bf2f(qb0v.x), bf2f(qb0v.y), bf2f(qb0v.z), bf2f(qb0v.w), bf2f(qc0) };
    float qb1[9] = { bf2f(qa1.x), bf2f(qa1.y), bf2f(qa1.z), bf2f(qa1.w),
                     bf2f(qb1v.x), bf2f(qb1v.y), bf2f(qb1v.z), bf2f(qb1v.w), bf2f(qc1) };

    float s0[9], s1[9];
    #pragma unroll
    for (int n = 0; n < 9; ++n) {
        const int m0 = (n / 3) * 4 + (n % 3);         // pixel0's neighbor position
        const uint4 kv0 = kv[m0], kv1 = kv[m0 + 1];   // pixel1: shifted one column
        float a = fmaf(q00, lo16f(kv0.x), fmaf(q01, hi16f(kv0.x),
                  fmaf(q02, lo16f(kv0.y), q03 * hi16f(kv0.y))));
        float b = fmaf(q10, lo16f(kv1.x), fmaf(q11, hi16f(kv1.x),
                  fmaf(q12, lo16f(kv1.y), q13 * hi16f(kv1.y))));
        a += __shfl_xor(a, 1); a += __shfl_xor(a, 2); a += __shfl_xor(a, 4);
        b += __shfl_xor(b, 1); b += __shfl_xor(b, 2); b += __shfl_xor(b, 4);
        s0[n] = a + qb0[n];
        s1[n] = b + qb1[n];
    }

    float mx0 = s0[0], mx1 = s1[0];
    #pragma unroll
    for (int n = 1; n < 9; ++n) { mx0 = fmaxf(mx0, s0[n]); mx1 = fmaxf(mx1, s1[n]); }
    float sum0 = 0.f, sum1 = 0.f;
    #pragma unroll
    for (int n = 0; n < 9; ++n) {
        s0[n] = __expf(s0[n] - mx0); sum0 += s0[n];
        s1[n] = __expf(s1[n] - mx1); sum1 += s1[n];
    }
    const float inv0 = 1.0f / sum0, inv1 = 1.0f / sum1;
    const float Ej0 = (s0[2] + s0[5] + s0[8]) - (s0[0] + s0[3] + s0[6]);
    const float Ei0 = (s0[6] + s0[7] + s0[8]) - (s0[0] + s0[1] + s0[2]);
    const float Ej1 = (s1[2] + s1[5] + s1[8]) - (s1[0] + s1[3] + s1[6]);
    const float Ei1 = (s1[6] + s1[7] + s1[8]) - (s1[0] + s1[1] + s1[2]);

    float o00 = 0.f, o01 = 0.f, o02 = 0.f, o03 = 0.f;
    float o10 = 0.f, o11 = 0.f, o12 = 0.f, o13 = 0.f;
    #pragma unroll
    for (int n = 0; n < 9; ++n) {
        const int m0 = (n / 3) * 4 + (n % 3);
        const uint4 kv0 = kv[m0], kv1 = kv[m0 + 1];
        o00 = fmaf(s0[n], lo16f(kv0.z), o00);
        o01 = fmaf(s0[n], hi16f(kv0.z), o01);
        o02 = fmaf(s0[n], lo16f(kv0.w), o02);
        o03 = fmaf(s0[n], hi16f(kv0.w), o03);
        o10 = fmaf(s1[n], lo16f(kv1.z), o10);
        o11 = fmaf(s1[n], hi16f(kv1.z), o11);
        o12 = fmaf(s1[n], lo16f(kv1.w), o12);
        o13 = fmaf(s1[n], hi16f(kv1.w), o13);
    }
    const float4 w0 = *reinterpret_cast<const float4*>(wvTab + idx);
    const float4 w1 = *reinterpret_cast<const float4*>(wvTab + 256 + idx);
    const float4 w2 = *reinterpret_cast<const float4*>(wvTab + 512 + idx);
    ushort4 ov0, ov1;
    ov0.x = bfbits(fmaf(Ej0, w0.x, fmaf(Ei0, w1.x, o00)) * inv0 + w2.x);
    ov0.y = bfbits(fmaf(Ej0, w0.y, fmaf(Ei0, w1.y, o01)) * inv0 + w2.y);
    ov0.z = bfbits(fmaf(Ej0, w0.z, fmaf(Ei0, w1.z, o02)) * inv0 + w2.z);
    ov0.w = bfbits(fmaf(Ej0, w0.w, fmaf(Ei0, w1.w, o03)) * inv0 + w2.w);
    ov1.x = bfbits(fmaf(Ej1, w0.x, fmaf(Ei1, w1.x, o10)) * inv1 + w2.x);
    ov1.y = bfbits(fmaf(Ej1, w0.y, fmaf(Ei1, w1.y, o11)) * inv1 + w2.y);
    ov1.z = bfbits(fmaf(Ej1, w0.z, fmaf(Ei1, w1.z, o12)) * inv1 + w2.z);
    ov1.w = bfbits(fmaf(Ej1, w0.w, fmaf(Ei1, w1.w, o13)) * inv1 + w2.w);
    *reinterpret_cast<ushort4*>(O + (size_t)p0 * 256 + idx) = ov0;
    *reinterpret_cast<ushort4*>(O + (size_t)(p0 + 1) * 256 + idx) = ov1;
}

// ---------------------------------------------------------------- launch
extern "C" void kernel_launch(void* const* d_in, const int* in_sizes, int n_in,
                              void* d_out, int out_size, void* d_ws, size_t ws_size,
                              hipStream_t stream) {
    (void)in_sizes; (void)n_in; (void)out_size; (void)ws_size;
    const float* x  = (const float*)d_in[0];
    const float* Wq = (const float*)d_in[1];
    const float* bq = (const float*)d_in[2];
    const float* Wk = (const float*)d_in[3];
    const float* bk = (const float*)d_in[4];
    const float* Wv = (const float*)d_in[5];
    const float* bv = (const float*)d_in[6];
    const float* Wo = (const float*)d_in[7];
    const float* bo = (const float*)d_in[8];

    char* ws = (char*)d_ws;
    // ws layout (O overlaps dead xb; total ~147.3 MB):
    __hip_bfloat16* xb    = (__hip_bfloat16*)(ws + 0);           // 25,165,824 B
    __hip_bfloat16* O     = (__hip_bfloat16*)(ws + 0);           // 33,554,432 B (xb dead by then)
    __hip_bfloat16* QKV   = (__hip_bfloat16*)(ws + 33554432);    // 65537*864*2 = 113,247,936 B
    __hip_bfloat16* WqkvT = (__hip_bfloat16*)(ws + 146802368);   // 896*192*2 = 344,064
    __hip_bfloat16* WoT   = (__hip_bfloat16*)(ws + 147146432);   // 192*256*2 = 98,304
    float* qkvBias        = (float*)(ws + 147244736);            // 896*4 = 3,584
    float* wvTab          = (float*)(ws + 147248320);            // 3*256*4 = 3,072

    k_convert_x<<<4096, 256, 0, stream>>>(x, (ushort4*)xb, 12582912 / 4);
    k_pack<<<874, 256, 0, stream>>>(Wq, Wk, Wv, Wo, bq, bk, bv, WqkvT, WoT, qkvBias, wvTab, QKV);
    // QKV+QB projection: [65536,192] x [192,896(864 used)] -> bf16, stride 864
    k_gemm_lds<128, 128, 2, 2, 192, 864, 7, false, true>
        <<<3584, 256, 0, stream>>>(xb, WqkvT, (void*)QKV, qkvBias, QSTRIDE);
    // attention: 2 adjacent pixels per wave, 4 waves per block
    k_attn<<<8192, 256, 0, stream>>>(QKV, wvTab, O);
    // output projection: [65536,256] x [256,192] -> f32 + bo
    k_gemm_lds<128, 64, 2, 2, 256, 192, 3, true, true>
        <<<1536, 256, 0, stream>>>(O, WoT, d_out, bo, 192);
}